// Round 5
// baseline (3576.448 us; speedup 1.0000x reference)
//
#include <hip/hip_runtime.h>
#include <cstdint>
#include <cstddef>

typedef unsigned short u16;
typedef unsigned int u32;
typedef unsigned long long u64;

typedef short short8 __attribute__((ext_vector_type(8)));
typedef float floatx4 __attribute__((ext_vector_type(4)));
typedef u64 u64x2 __attribute__((ext_vector_type(2)));

// Problem constants: B=32, T=512, D=256, H=256, 4H=1024, C=32
// Workspace layout (bytes)
#define O_EMB    0ull                 // emb bf16 [16384][256]
#define O_XG     8388608ull           // xg bf16 [2][512][256 dim][2 half][4 lq][4 gate] u64-of-4-batches
#define O_HS     75497472ull          // hs bf16 [2][16384][256]
#define O_LOGITS 92340224ull          // logits f32 [16384][32]; ALSO WhT bf16 [2][1024][256] (live k0->k3 only)
#define O_WIT    94437504ull          // WiT bf16 [2][1024][256]
#define O_OUTW   95486080ull          // outW bf16 [512][32]
#define WS_NEED  95520896ull

__device__ __forceinline__ u16 f2bf(float x) {
    u32 u = __float_as_uint(x);
    u += 0x7fffu + ((u >> 16) & 1u);
    return (u16)(u >> 16);
}
__device__ __forceinline__ float bf2f(u16 v) { return __uint_as_float(((u32)v) << 16); }
__device__ __forceinline__ float sigm(float x) { return 1.0f / (1.0f + __expf(-x)); }
__device__ __forceinline__ float tanh_f(float x) {
    x = fminf(30.0f, fmaxf(-30.0f, x));
    float e = __expf(-2.0f * x);
    return (1.0f - e) / (1.0f + e);
}

// ---------------- K0: Wi/Wh -> transposed bf16 [n][k], out_W -> bf16 ---------------
__global__ __launch_bounds__(256) void k0_prep(const float* __restrict__ Wi_f, const float* __restrict__ Wi_b,
                                               const float* __restrict__ Wh_f, const float* __restrict__ Wh_b,
                                               const float* __restrict__ out_W,
                                               u16* __restrict__ WiT, u16* __restrict__ WhT,
                                               u16* __restrict__ outWb) {
    int id = blockIdx.x * 256 + threadIdx.x;   // grid 4160*256 = 1064960 exact
    if (id < 524288) {
        int d = id >> 18;
        int rem = id & 262143;
        int k = rem >> 10;
        int n = rem & 1023;
        const float* Wi = d ? Wi_b : Wi_f;
        WiT[(size_t)d * 262144 + (size_t)n * 256 + k] = f2bf(Wi[(size_t)k * 1024 + n]);
    } else if (id < 540672) {
        int id2 = id - 524288;                 // < 16384
        outWb[id2] = f2bf(out_W[id2]);
    } else {
        int id2 = id - 540672;                 // < 524288
        int d = id2 >> 18;
        int rem = id2 & 262143;
        int k = rem >> 10;
        int n = rem & 1023;
        const float* Wh = d ? Wh_b : Wh_f;
        WhT[(size_t)d * 262144 + (size_t)n * 256 + k] = f2bf(Wh[(size_t)k * 1024 + n]);
    }
}

// ---------------- K1: embedding gather -> emb bf16 [r=t*32+b][256] -----------------
__global__ __launch_bounds__(256) void k1_embed(const int* __restrict__ chars, const int* __restrict__ bigrams,
                                                const float* __restrict__ ct, const float* __restrict__ bt,
                                                u16* __restrict__ emb) {
    int idx = blockIdx.x * 256 + threadIdx.x;  // grid 8192*256 = 2097152 = 16384*128
    int r = idx >> 7;
    int p2 = (idx & 127) << 1;
    int t = r >> 5, b = r & 31;
    const float* src;
    if (p2 < 128) src = ct + (size_t)chars[b * 512 + t] * 128 + p2;
    else          src = bt + (size_t)bigrams[b * 512 + t] * 128 + (p2 - 128);
    float2 v = *(const float2*)(const void*)src;
    u32 pk = (u32)f2bf(v.x) | ((u32)f2bf(v.y) << 16);
    *(u32*)(void*)(emb + (size_t)r * 256 + p2) = pk;
}

// ---------------- K2: xg = emb @ Wi_d + b_d  (bf16 MFMA) ---------------------------
// Store layout: u64 index = (((t*256 + c)*2 + half)*4 + lq)*4 + g  (4 batches/u64)
// so k3's 4 gate-words per thread are 32B contiguous.
__global__ __launch_bounds__(256) void k2_gemm(const u16* __restrict__ emb, const u16* __restrict__ WiT,
                                               const float* __restrict__ b_f, const float* __restrict__ b_b,
                                               u16* __restrict__ xg) {
    int mbase = blockIdx.x * 64;
    int nbase = blockIdx.y * 64;
    int d = blockIdx.z;
    const u16* Bt = WiT + (size_t)d * 262144;
    const float* bias = d ? b_b : b_f;
    u64* xgd = (u64*)(void*)(xg + (size_t)d * 16777216ull);
    int tid = threadIdx.x;
    int wv = tid >> 6, l = tid & 63, lm = l & 15, lq = l >> 4;
    floatx4 acc[4] = {{0,0,0,0},{0,0,0,0},{0,0,0,0},{0,0,0,0}};
    int arow = mbase + wv * 16 + lm;
#pragma unroll
    for (int kc = 0; kc < 8; ++kc) {
        int k0 = kc * 32 + lq * 8;
        short8 a = *(const short8*)(const void*)(emb + (size_t)arow * 256 + k0);
#pragma unroll
        for (int nt = 0; nt < 4; ++nt) {
            short8 bb = *(const short8*)(const void*)(Bt + (size_t)(nbase + nt * 16 + lm) * 256 + k0);
            acc[nt] = __builtin_amdgcn_mfma_f32_16x16x32_bf16(a, bb, acc[nt], 0, 0, 0);
        }
    }
    // rows rr0..rr0+3 lie in one 32-row (one t) block since mbase is 64-aligned
    int rr0 = mbase + wv * 16 + lq * 4;
    int tt = rr0 >> 5, b0 = rr0 & 31;
    int half = b0 >> 4, lqq = (b0 >> 2) & 3;
#pragma unroll
    for (int nt = 0; nt < 4; ++nt) {
        int n = nbase + nt * 16 + lm;
        int g = n >> 8, c = n & 255;
        float bv = bias[n];
        u64 pk = (u64)f2bf(acc[nt][0] + bv)
               | ((u64)f2bf(acc[nt][1] + bv) << 16)
               | ((u64)f2bf(acc[nt][2] + bv) << 32)
               | ((u64)f2bf(acc[nt][3] + bv) << 48);
        xgd[((((size_t)tt * 256 + c) * 2 + half) * 4 + lqq) * 4 + g] = pk;
    }
}

// ---------------- K3: BiLSTM recurrence, batch-split (NO inter-block sync) ---------
// 4 blocks: (dir = bid>>1, half = bid&1). 256 threads = 4 waves = 1 wave/SIMD,
// amdgpu_waves_per_eu(1,1) -> FULL 512-register combined (VGPR+AGPR) budget/wave.
// Each wave owns 256 gate-cols (64 per gate = 4 n-tile phases).
// Gates 0..2 B-frags in registers: whb[3][4][8] = 384 regs (MFMA-B-only operands,
// AGPR-eligible on gfx950's unified file). Gate 3 B-frags in LDS (128 KB,
// per-lane fragment order -> minimum-cost ds_read_b128).
// Per phase: acc init from xg (rolling 1-phase prefetch), 8 kc x {A ds_read,
// B3 ds_read, 4 MFMA}, then register-local activations; c-state in VGPRs.
// h exchanged via double-buffered LDS; one s_barrier + lgkmcnt(0) per step;
// global hs history stores left in flight across the barrier.
__global__ __attribute__((amdgpu_waves_per_eu(1, 1))) __launch_bounds__(256)
void k3_lstm(const u16* __restrict__ xg, const u16* __restrict__ WhT,
             const int* __restrict__ seq_len, u16* __restrict__ hs) {
    int bid = blockIdx.x;
    int dir = bid >> 1;
    int half = bid & 1;
    const char* xgb = (const char*)xg + (size_t)dir * 33554432ull;   // 32MB per dir
    const u16* whd = WhT + (size_t)dir * 262144ull;
    u16* hsd = hs + (size_t)dir * 4194304ull;

    __shared__ __align__(16) u16 wh3[65536];        // 128 KB: g=3 B-frags [wv][nt][kc][lane]
    __shared__ __align__(16) u16 h_all[2][4224];    // 16.5 KB: h dbuf [batch16][pitch 264]

    int tid = threadIdx.x;
    int wv = tid >> 6;                              // 0..3
    int l = tid & 63;
    int lm = l & 15, lq = l >> 4;
    int cb = wv * 64 + lm;                          // phase nt col = cb + nt*16

    // B-frags for gates 0..2 in registers: whb[g][nt][kc] (384 regs)
    short8 whb[3][4][8];
#pragma unroll
    for (int g = 0; g < 3; ++g)
#pragma unroll
        for (int nt = 0; nt < 4; ++nt)
#pragma unroll
            for (int kc = 0; kc < 8; ++kc)
                whb[g][nt][kc] = *(const short8*)(const void*)(
                    whd + (size_t)(g * 256 + cb + nt * 16) * 256 + kc * 32 + lq * 8);
    // gate 3 B-frags -> LDS, per-lane fragment order (contiguous 1KB per wave-read)
#pragma unroll
    for (int nt = 0; nt < 4; ++nt)
#pragma unroll
        for (int kc = 0; kc < 8; ++kc) {
            short8 f3 = *(const short8*)(const void*)(
                whd + (size_t)(768 + cb + nt * 16) * 256 + kc * 32 + lq * 8);
            ((short8*)(void*)wh3)[((wv * 4 + nt) * 8 + kc) * 64 + l] = f3;
        }

    float cst[4][4];   // [nt][r] — all indices compile-time (fully unrolled)
#pragma unroll
    for (int nt = 0; nt < 4; ++nt)
#pragma unroll
        for (int r = 0; r < 4; ++r) cst[nt][r] = 0.0f;
    u32 Lp0, Lp1;
    {
        int L0 = seq_len[half * 16 + lq * 4 + 0];
        int L1 = seq_len[half * 16 + lq * 4 + 1];
        int L2 = seq_len[half * 16 + lq * 4 + 2];
        int L3 = seq_len[half * 16 + lq * 4 + 3];
        Lp0 = (u32)L0 | ((u32)L1 << 16);
        Lp1 = (u32)L2 | ((u32)L3 << 16);
    }

    for (int i = tid; i < 4224; i += 256) h_all[0][i] = 0;   // h_{-1} = 0
    __syncthreads();

    const int aoff = lm * 264 + lq * 8;   // A-frag: row=batch lm, k=kc*32+lq*8..+8
    const int hrow = lq * 4;
    // per-thread xg byte offset for phase 0 (phase nt adds nt*4096; 4 gate-u64s = 32B)
    const u32 xoff0 = ((((u32)cb * 2 + (u32)half) * 4 + (u32)lq) * 4) * 8;

    // prologue: prefetch step-0 phase-0 xg (2 x 16B)
    {
        int t0 = dir ? 511 : 0;
        // fallthrough into loop-carried xc0/xc1
    }
    int tpro = dir ? 511 : 0;
    u64x2 xc0 = *(const u64x2*)(const void*)(xgb + (size_t)tpro * 65536 + xoff0);
    u64x2 xc1 = *(const u64x2*)(const void*)(xgb + (size_t)tpro * 65536 + xoff0 + 16);

    for (int s = 0; s < 512; ++s) {
        int t = dir ? (511 - s) : s;
        int tn = (s < 511) ? (dir ? (510 - s) : (s + 1)) : t;   // next step (clamped)
        const u16* hb = h_all[s & 1];
        u16* hw = h_all[(s & 1) ^ 1];
        u16* hsbase = hsd + ((size_t)(t * 32 + half * 16 + hrow)) * 256 + cb;

#pragma unroll
        for (int nt = 0; nt < 4; ++nt) {
            // rolling prefetch: next phase's xg (or next step's phase 0)
            int ntn = (nt + 1) & 3;
            const char* xr = xgb + (size_t)((nt < 3) ? t : tn) * 65536 + xoff0 + ntn * 4096;
            u64x2 xn0 = *(const u64x2*)(const void*)(xr);
            u64x2 xn1 = *(const u64x2*)(const void*)(xr + 16);

            floatx4 aI, aF, aG, aO;
#pragma unroll
            for (int r = 0; r < 4; ++r) {
                aI[r] = bf2f((u16)(xc0.x >> (16 * r)));
                aF[r] = bf2f((u16)(xc0.y >> (16 * r)));
                aG[r] = bf2f((u16)(xc1.x >> (16 * r)));
                aO[r] = bf2f((u16)(xc1.y >> (16 * r)));
            }
#pragma unroll
            for (int kc = 0; kc < 8; ++kc) {
                short8 a = *(const short8*)(const void*)(hb + aoff + kc * 32);
                short8 b3 = ((const short8*)(const void*)wh3)[((wv * 4 + nt) * 8 + kc) * 64 + l];
                aI = __builtin_amdgcn_mfma_f32_16x16x32_bf16(a, whb[0][nt][kc], aI, 0, 0, 0);
                aF = __builtin_amdgcn_mfma_f32_16x16x32_bf16(a, whb[1][nt][kc], aF, 0, 0, 0);
                aG = __builtin_amdgcn_mfma_f32_16x16x32_bf16(a, whb[2][nt][kc], aG, 0, 0, 0);
                aO = __builtin_amdgcn_mfma_f32_16x16x32_bf16(a, b3, aO, 0, 0, 0);
            }
#pragma unroll
            for (int r = 0; r < 4; ++r) {
                float ig = sigm(aI[r]), fg = sigm(aF[r]), gt = tanh_f(aG[r]), og = sigm(aO[r]);
                float cn = fg * cst[nt][r] + ig * gt;
                float hn = og * tanh_f(cn);
                int Lv = (int)(((r < 2) ? (Lp0 >> (16 * (r & 1))) : (Lp1 >> (16 * (r & 1)))) & 0xffffu);
                if (dir && t >= Lv) { cn = cst[nt][r]; hn = 0.0f; }   // backward: masked suffix stays 0
                cst[nt][r] = cn;
                u16 hbf = f2bf(hn);
                hw[(hrow + r) * 264 + cb + nt * 16] = hbf;            // h for next step (LDS)
                hsbase[(size_t)r * 256 + nt * 16] = hbf;              // history for k4 (in flight)
            }
            xc0 = xn0;
            xc1 = xn1;
        }

        // Barrier WITHOUT vmcnt drain: only LDS writes must be visible.
        asm volatile("s_waitcnt lgkmcnt(0)" ::: "memory");
        __builtin_amdgcn_sched_barrier(0);
        __builtin_amdgcn_s_barrier();
        __builtin_amdgcn_sched_barrier(0);
    }
}

// ---------------- K4: logits = log_softmax([hf;hb] @ out_W + out_b) ---------------
__global__ __launch_bounds__(256) void k4_proj(const u16* __restrict__ hs, const u16* __restrict__ outWb,
                                               const float* __restrict__ out_b, float* __restrict__ logits) {
    int r = blockIdx.x * 8 + (threadIdx.x >> 5);
    int n = threadIdx.x & 31;
    const u16* hf = hs + (size_t)r * 256;
    const u16* hbk = hs + 4194304ull + (size_t)r * 256;
    float acc = out_b[n];
#pragma unroll 4
    for (int k = 0; k < 256; k += 2) {
        u32 hv = *(const u32*)(const void*)(hf + k);
        acc += bf2f((u16)hv) * bf2f(outWb[k * 32 + n]);
        acc += bf2f((u16)(hv >> 16)) * bf2f(outWb[(k + 1) * 32 + n]);
    }
#pragma unroll 4
    for (int k = 0; k < 256; k += 2) {
        u32 hv = *(const u32*)(const void*)(hbk + k);
        acc += bf2f((u16)hv) * bf2f(outWb[(256 + k) * 32 + n]);
        acc += bf2f((u16)(hv >> 16)) * bf2f(outWb[(257 + k) * 32 + n]);
    }
    float m = acc;
#pragma unroll
    for (int d2 = 16; d2 >= 1; d2 >>= 1) m = fmaxf(m, __shfl_xor(m, d2, 32));
    float s = __expf(acc - m);
#pragma unroll
    for (int d2 = 16; d2 >= 1; d2 >>= 1) s += __shfl_xor(s, d2, 32);
    logits[(size_t)r * 32 + n] = acc - m - __logf(s);
}

// ---------------- K5: CRF forward + gold score -> out[b] --------------------------
__global__ __launch_bounds__(256) void k5_crf(const float* __restrict__ logits, const int* __restrict__ target,
                                              const int* __restrict__ seq_len, const float* __restrict__ trans,
                                              const float* __restrict__ start_trans, const float* __restrict__ end_trans,
                                              float* __restrict__ out) {
    int b = blockIdx.x;
    int tid = threadIdx.x;
    int L = seq_len[b];
    __shared__ float alpha[32];
    __shared__ float red[4];
    __shared__ float goldsh;

    // gold path score
    float part = 0.0f;
    for (int t = tid; t < 512; t += 256) {
        if (t < L) {
            int tg = target[b * 512 + t];
            part += logits[((size_t)(t * 32 + b)) * 32 + tg];
            if (t >= 1) part += trans[target[b * 512 + t - 1] * 32 + tg];
        }
    }
#pragma unroll
    for (int d2 = 32; d2 >= 1; d2 >>= 1) part += __shfl_xor(part, d2, 64);
    if ((tid & 63) == 0) red[tid >> 6] = part;
    __syncthreads();
    if (tid == 0) {
        float g = red[0] + red[1] + red[2] + red[3];
        g += start_trans[target[b * 512]];
        g += end_trans[target[b * 512 + L - 1]];
        goldsh = g;
    }
    if (tid < 32) alpha[tid] = logits[(size_t)b * 32 + tid] + start_trans[tid];
    __syncthreads();

    int j = tid >> 3, uu = tid & 7;
    float tr4[4];
#pragma unroll
    for (int r = 0; r < 4; ++r) tr4[r] = trans[(uu * 4 + r) * 32 + j];
    float e_next = logits[((size_t)(32 + b)) * 32 + j];
    for (int t = 1; t < 512; ++t) {
        float e = e_next;
        if (t < 511) e_next = logits[((size_t)((t + 1) * 32 + b)) * 32 + j];
        float a0 = alpha[uu * 4 + 0] + tr4[0];
        float a1 = alpha[uu * 4 + 1] + tr4[1];
        float a2 = alpha[uu * 4 + 2] + tr4[2];
        float a3 = alpha[uu * 4 + 3] + tr4[3];
        float m = fmaxf(fmaxf(a0, a1), fmaxf(a2, a3));
#pragma unroll
        for (int d2 = 4; d2 >= 1; d2 >>= 1) m = fmaxf(m, __shfl_xor(m, d2, 8));
        float ss = __expf(a0 - m) + __expf(a1 - m) + __expf(a2 - m) + __expf(a3 - m);
#pragma unroll
        for (int d2 = 4; d2 >= 1; d2 >>= 1) ss += __shfl_xor(ss, d2, 8);
        float nv = e + m + __logf(ss);
        __syncthreads();
        if (uu == 0 && t < L) alpha[j] = nv;
        __syncthreads();
    }
    if (tid < 32) {
        float v = alpha[tid] + end_trans[tid];
        float m = v;
#pragma unroll
        for (int d2 = 16; d2 >= 1; d2 >>= 1) m = fmaxf(m, __shfl_xor(m, d2, 32));
        float s2 = __expf(v - m);
#pragma unroll
        for (int d2 = 16; d2 >= 1; d2 >>= 1) s2 += __shfl_xor(s2, d2, 32);
        if (tid == 0) out[b] = m + __logf(s2) - goldsh;
    }
}

extern "C" void kernel_launch(void* const* d_in, const int* in_sizes, int n_in,
                              void* d_out, int out_size, void* d_ws, size_t ws_size,
                              hipStream_t stream) {
    if (ws_size < WS_NEED) return;  // workspace too small: fail cleanly, no OOB
    const int* chars = (const int*)d_in[0];
    const int* bigrams = (const int*)d_in[1];
    const int* seq_len = (const int*)d_in[2];
    const int* target = (const int*)d_in[3];
    const float* char_table = (const float*)d_in[4];
    const float* bigram_table = (const float*)d_in[5];
    const float* Wi_f = (const float*)d_in[6];
    const float* Wh_f = (const float*)d_in[7];
    const float* b_f = (const float*)d_in[8];
    const float* Wi_b = (const float*)d_in[9];
    const float* Wh_b = (const float*)d_in[10];
    const float* b_b = (const float*)d_in[11];
    const float* out_W = (const float*)d_in[12];
    const float* out_b = (const float*)d_in[13];
    const float* trans = (const float*)d_in[14];
    const float* start_trans = (const float*)d_in[15];
    const float* end_trans = (const float*)d_in[16];

    char* ws = (char*)d_ws;
    u16* emb = (u16*)(ws + O_EMB);
    u16* xg = (u16*)(ws + O_XG);
    u16* hs = (u16*)(ws + O_HS);
    float* logits = (float*)(ws + O_LOGITS);
    u16* WhT = (u16*)(ws + O_LOGITS);    // parked in logits region; dead before k4 writes logits
    u16* WiT = (u16*)(ws + O_WIT);
    u16* outWb = (u16*)(ws + O_OUTW);

    hipLaunchKernelGGL(k0_prep, dim3(4160), dim3(256), 0, stream, Wi_f, Wi_b, Wh_f, Wh_b, out_W, WiT, WhT, outWb);
    hipLaunchKernelGGL(k1_embed, dim3(8192), dim3(256), 0, stream, chars, bigrams, char_table, bigram_table, emb);
    hipLaunchKernelGGL(k2_gemm, dim3(256, 16, 2), dim3(256), 0, stream, emb, WiT, b_f, b_b, xg);
    hipLaunchKernelGGL(k3_lstm, dim3(4), dim3(256), 0, stream, xg, WhT, seq_len, hs);
    hipLaunchKernelGGL(k4_proj, dim3(2048), dim3(256), 0, stream, hs, outWb, out_b, logits);
    hipLaunchKernelGGL(k5_crf, dim3(32), dim3(256), 0, stream, logits, target, seq_len, trans, start_trans, end_trans,
                       (float*)d_out);
}

// Round 6
// 3312.793 us; speedup vs baseline: 1.0796x; 1.0796x over previous
//
#include <hip/hip_runtime.h>
#include <cstdint>
#include <cstddef>

typedef unsigned short u16;
typedef unsigned int u32;
typedef unsigned long long u64;

typedef short short8 __attribute__((ext_vector_type(8)));
typedef float floatx4 __attribute__((ext_vector_type(4)));
typedef u64 u64x2 __attribute__((ext_vector_type(2)));

// Problem constants: B=32, T=512, D=256, H=256, 4H=1024, C=32
// Workspace layout (bytes)
#define O_EMB    0ull                 // emb bf16 [16384][256]
#define O_XG     8388608ull           // xg bf16 [2][512][256 dim][2 half][4 lq][4 gate] u64-of-4-batches
#define O_HS     75497472ull          // hs bf16 [2][16384][256]
#define O_LOGITS 92340224ull          // logits f32 [16384][32]; ALSO WhT bf16 [2][1024][256] (live k0->k3 only)
#define O_WIT    94437504ull          // WiT bf16 [2][1024][256]
#define O_OUTW   95486080ull          // outW bf16 [512][32]
#define WS_NEED  95520896ull

__device__ __forceinline__ u16 f2bf(float x) {
    u32 u = __float_as_uint(x);
    u += 0x7fffu + ((u >> 16) & 1u);
    return (u16)(u >> 16);
}
__device__ __forceinline__ float bf2f(u16 v) { return __uint_as_float(((u32)v) << 16); }
__device__ __forceinline__ float sigm(float x) { return 1.0f / (1.0f + __expf(-x)); }
__device__ __forceinline__ float tanh_f(float x) {
    x = fminf(30.0f, fmaxf(-30.0f, x));
    float e = __expf(-2.0f * x);
    return (1.0f - e) / (1.0f + e);
}

// MFMA with the B operand pinned to AGPRs ("a" constraint). Hazard nops are
// explicit because the compiler's hazard recognizer can't see inside asm:
//  - _first: s_nop 3 covers VALU(acc-init) -> MFMA src2 wait states
//  - _mid:   acc chaining MFMA->MFMA src2 needs none
//  - _last:  trailing s_nop 7 x2 covers MFMA dst -> VALU read wait states
__device__ __forceinline__ void mfma_ag_first(floatx4& c, short8 a, short8 w) {
    asm volatile("s_nop 3\n\tv_mfma_f32_16x16x32_bf16 %0, %1, %2, %0"
                 : "+v"(c) : "v"(a), "a"(w));
}
__device__ __forceinline__ void mfma_ag_mid(floatx4& c, short8 a, short8 w) {
    asm volatile("v_mfma_f32_16x16x32_bf16 %0, %1, %2, %0"
                 : "+v"(c) : "v"(a), "a"(w));
}
__device__ __forceinline__ void mfma_ag_last(floatx4& c, short8 a, short8 w) {
    asm volatile("v_mfma_f32_16x16x32_bf16 %0, %1, %2, %0\n\ts_nop 7\n\ts_nop 7"
                 : "+v"(c) : "v"(a), "a"(w));
}

// ---------------- K0: Wi/Wh -> transposed bf16 [n][k], out_W -> bf16 ---------------
__global__ __launch_bounds__(256) void k0_prep(const float* __restrict__ Wi_f, const float* __restrict__ Wi_b,
                                               const float* __restrict__ Wh_f, const float* __restrict__ Wh_b,
                                               const float* __restrict__ out_W,
                                               u16* __restrict__ WiT, u16* __restrict__ WhT,
                                               u16* __restrict__ outWb) {
    int id = blockIdx.x * 256 + threadIdx.x;   // grid 4160*256 = 1064960 exact
    if (id < 524288) {
        int d = id >> 18;
        int rem = id & 262143;
        int k = rem >> 10;
        int n = rem & 1023;
        const float* Wi = d ? Wi_b : Wi_f;
        WiT[(size_t)d * 262144 + (size_t)n * 256 + k] = f2bf(Wi[(size_t)k * 1024 + n]);
    } else if (id < 540672) {
        int id2 = id - 524288;                 // < 16384
        outWb[id2] = f2bf(out_W[id2]);
    } else {
        int id2 = id - 540672;                 // < 524288
        int d = id2 >> 18;
        int rem = id2 & 262143;
        int k = rem >> 10;
        int n = rem & 1023;
        const float* Wh = d ? Wh_b : Wh_f;
        WhT[(size_t)d * 262144 + (size_t)n * 256 + k] = f2bf(Wh[(size_t)k * 1024 + n]);
    }
}

// ---------------- K1: embedding gather -> emb bf16 [r=t*32+b][256] -----------------
__global__ __launch_bounds__(256) void k1_embed(const int* __restrict__ chars, const int* __restrict__ bigrams,
                                                const float* __restrict__ ct, const float* __restrict__ bt,
                                                u16* __restrict__ emb) {
    int idx = blockIdx.x * 256 + threadIdx.x;  // grid 8192*256 = 2097152 = 16384*128
    int r = idx >> 7;
    int p2 = (idx & 127) << 1;
    int t = r >> 5, b = r & 31;
    const float* src;
    if (p2 < 128) src = ct + (size_t)chars[b * 512 + t] * 128 + p2;
    else          src = bt + (size_t)bigrams[b * 512 + t] * 128 + (p2 - 128);
    float2 v = *(const float2*)(const void*)src;
    u32 pk = (u32)f2bf(v.x) | ((u32)f2bf(v.y) << 16);
    *(u32*)(void*)(emb + (size_t)r * 256 + p2) = pk;
}

// ---------------- K2: xg = emb @ Wi_d + b_d  (bf16 MFMA) ---------------------------
// Store layout: u64 index = (((t*256 + c)*2 + half)*4 + lq)*4 + g  (4 batches/u64)
// so k3's 4 gate-words per thread are 32B contiguous.
__global__ __launch_bounds__(256) void k2_gemm(const u16* __restrict__ emb, const u16* __restrict__ WiT,
                                               const float* __restrict__ b_f, const float* __restrict__ b_b,
                                               u16* __restrict__ xg) {
    int mbase = blockIdx.x * 64;
    int nbase = blockIdx.y * 64;
    int d = blockIdx.z;
    const u16* Bt = WiT + (size_t)d * 262144;
    const float* bias = d ? b_b : b_f;
    u64* xgd = (u64*)(void*)(xg + (size_t)d * 16777216ull);
    int tid = threadIdx.x;
    int wv = tid >> 6, l = tid & 63, lm = l & 15, lq = l >> 4;
    floatx4 acc[4] = {{0,0,0,0},{0,0,0,0},{0,0,0,0},{0,0,0,0}};
    int arow = mbase + wv * 16 + lm;
#pragma unroll
    for (int kc = 0; kc < 8; ++kc) {
        int k0 = kc * 32 + lq * 8;
        short8 a = *(const short8*)(const void*)(emb + (size_t)arow * 256 + k0);
#pragma unroll
        for (int nt = 0; nt < 4; ++nt) {
            short8 bb = *(const short8*)(const void*)(Bt + (size_t)(nbase + nt * 16 + lm) * 256 + k0);
            acc[nt] = __builtin_amdgcn_mfma_f32_16x16x32_bf16(a, bb, acc[nt], 0, 0, 0);
        }
    }
    // rows rr0..rr0+3 lie in one 32-row (one t) block since mbase is 64-aligned
    int rr0 = mbase + wv * 16 + lq * 4;
    int tt = rr0 >> 5, b0 = rr0 & 31;
    int half = b0 >> 4, lqq = (b0 >> 2) & 3;
#pragma unroll
    for (int nt = 0; nt < 4; ++nt) {
        int n = nbase + nt * 16 + lm;
        int g = n >> 8, c = n & 255;
        float bv = bias[n];
        u64 pk = (u64)f2bf(acc[nt][0] + bv)
               | ((u64)f2bf(acc[nt][1] + bv) << 16)
               | ((u64)f2bf(acc[nt][2] + bv) << 32)
               | ((u64)f2bf(acc[nt][3] + bv) << 48);
        xgd[((((size_t)tt * 256 + c) * 2 + half) * 4 + lqq) * 4 + g] = pk;
    }
}

// ---------------- K3: BiLSTM recurrence, batch-split (NO inter-block sync) ---------
// 4 blocks: (dir = bid>>1, half = bid&1). 256 threads = 4 waves = 1 wave/SIMD,
// waves_per_eu(1,1): combined register budget 512/wave (arch <= 256 + AGPR <= 256).
// Weight placement (the binding constraint, r1-r5 lesson):
//   gate 0,1 B-frags -> AGPRs (exactly 256), FORCED via inline-asm MFMA "a" operands
//   gate 2   B-frags -> arch VGPRs (128), builtin MFMA
//   gate 3   B-frags -> LDS (128 KB, per-lane fragment order)
// Arch demand ~225 <= 240 proven grant; no value class left to spill.
// Per phase nt: acc init from xg (rolling prefetch), 8 kc x {A ds_read, g3 ds_read,
// 4 MFMA}, register-local activations; c-state in VGPRs.
// h exchanged via double-buffered LDS; one s_barrier + lgkmcnt(0) per step;
// global hs history stores left in flight across the barrier.
__global__ __attribute__((amdgpu_waves_per_eu(1, 1))) __launch_bounds__(256)
void k3_lstm(const u16* __restrict__ xg, const u16* __restrict__ WhT,
             const int* __restrict__ seq_len, u16* __restrict__ hs) {
    int bid = blockIdx.x;
    int dir = bid >> 1;
    int half = bid & 1;
    const char* xgb = (const char*)xg + (size_t)dir * 33554432ull;   // 32MB per dir
    const u16* whd = WhT + (size_t)dir * 262144ull;
    u16* hsd = hs + (size_t)dir * 4194304ull;

    __shared__ __align__(16) u16 wh3[65536];        // 128 KB: g=3 B-frags [wv][nt][kc][lane]
    __shared__ __align__(16) u16 h_all[2][4224];    // 16.5 KB: h dbuf [batch16][pitch 264]

    int tid = threadIdx.x;
    int wv = tid >> 6;                              // 0..3
    int l = tid & 63;
    int lm = l & 15, lq = l >> 4;
    int cb = wv * 64 + lm;                          // phase nt col = cb + nt*16

    // gate 0,1 B-frags -> AGPR-destined (asm-only uses); gate 2 -> arch VGPRs
    short8 whA0[4][8], whA1[4][8], whb2[4][8];
#pragma unroll
    for (int nt = 0; nt < 4; ++nt)
#pragma unroll
        for (int kc = 0; kc < 8; ++kc) {
            whA0[nt][kc] = *(const short8*)(const void*)(
                whd + (size_t)(0 * 256 + cb + nt * 16) * 256 + kc * 32 + lq * 8);
            whA1[nt][kc] = *(const short8*)(const void*)(
                whd + (size_t)(1 * 256 + cb + nt * 16) * 256 + kc * 32 + lq * 8);
            whb2[nt][kc] = *(const short8*)(const void*)(
                whd + (size_t)(2 * 256 + cb + nt * 16) * 256 + kc * 32 + lq * 8);
        }
    // gate 3 B-frags -> LDS, per-lane fragment order (contiguous 1KB per wave-read)
#pragma unroll
    for (int nt = 0; nt < 4; ++nt)
#pragma unroll
        for (int kc = 0; kc < 8; ++kc) {
            short8 f3 = *(const short8*)(const void*)(
                whd + (size_t)(768 + cb + nt * 16) * 256 + kc * 32 + lq * 8);
            ((short8*)(void*)wh3)[((wv * 4 + nt) * 8 + kc) * 64 + l] = f3;
        }

    float cst[4][4];   // [nt][r] — all indices compile-time (fully unrolled)
#pragma unroll
    for (int nt = 0; nt < 4; ++nt)
#pragma unroll
        for (int r = 0; r < 4; ++r) cst[nt][r] = 0.0f;
    u32 Lp0, Lp1;
    {
        int L0 = seq_len[half * 16 + lq * 4 + 0];
        int L1 = seq_len[half * 16 + lq * 4 + 1];
        int L2 = seq_len[half * 16 + lq * 4 + 2];
        int L3 = seq_len[half * 16 + lq * 4 + 3];
        Lp0 = (u32)L0 | ((u32)L1 << 16);
        Lp1 = (u32)L2 | ((u32)L3 << 16);
    }

    for (int i = tid; i < 4224; i += 256) h_all[0][i] = 0;   // h_{-1} = 0
    __syncthreads();

    const int aoff = lm * 264 + lq * 8;   // A-frag: row=batch lm, k=kc*32+lq*8..+8
    const int hrow = lq * 4;
    // per-thread xg byte offset for phase 0 (phase nt adds nt*4096; 4 gate-u64s = 32B)
    const u32 xoff0 = ((((u32)cb * 2 + (u32)half) * 4 + (u32)lq) * 4) * 8;

    // prologue: prefetch step-0 phase-0 xg (2 x 16B)
    int tpro = dir ? 511 : 0;
    u64x2 xc0 = *(const u64x2*)(const void*)(xgb + (size_t)tpro * 65536 + xoff0);
    u64x2 xc1 = *(const u64x2*)(const void*)(xgb + (size_t)tpro * 65536 + xoff0 + 16);

    for (int s = 0; s < 512; ++s) {
        int t = dir ? (511 - s) : s;
        int tn = (s < 511) ? (dir ? (510 - s) : (s + 1)) : t;   // next step (clamped)
        const u16* hb = h_all[s & 1];
        u16* hw = h_all[(s & 1) ^ 1];
        u16* hsbase = hsd + ((size_t)(t * 32 + half * 16 + hrow)) * 256 + cb;

#pragma unroll
        for (int nt = 0; nt < 4; ++nt) {
            // rolling prefetch: next phase's xg (or next step's phase 0)
            int ntn = (nt + 1) & 3;
            const char* xr = xgb + (size_t)((nt < 3) ? t : tn) * 65536 + xoff0 + ntn * 4096;
            u64x2 xn0 = *(const u64x2*)(const void*)(xr);
            u64x2 xn1 = *(const u64x2*)(const void*)(xr + 16);

            floatx4 aI, aF, aG, aO;
#pragma unroll
            for (int r = 0; r < 4; ++r) {
                aI[r] = bf2f((u16)(xc0.x >> (16 * r)));
                aF[r] = bf2f((u16)(xc0.y >> (16 * r)));
                aG[r] = bf2f((u16)(xc1.x >> (16 * r)));
                aO[r] = bf2f((u16)(xc1.y >> (16 * r)));
            }
#pragma unroll
            for (int kc = 0; kc < 8; ++kc) {
                short8 a = *(const short8*)(const void*)(hb + aoff + kc * 32);
                short8 b3 = ((const short8*)(const void*)wh3)[((wv * 4 + nt) * 8 + kc) * 64 + l];
                if (kc == 0) {
                    mfma_ag_first(aI, a, whA0[nt][kc]);
                    mfma_ag_first(aF, a, whA1[nt][kc]);
                } else if (kc == 7) {
                    mfma_ag_last(aI, a, whA0[nt][kc]);
                    mfma_ag_last(aF, a, whA1[nt][kc]);
                } else {
                    mfma_ag_mid(aI, a, whA0[nt][kc]);
                    mfma_ag_mid(aF, a, whA1[nt][kc]);
                }
                aG = __builtin_amdgcn_mfma_f32_16x16x32_bf16(a, whb2[nt][kc], aG, 0, 0, 0);
                aO = __builtin_amdgcn_mfma_f32_16x16x32_bf16(a, b3, aO, 0, 0, 0);
            }
#pragma unroll
            for (int r = 0; r < 4; ++r) {
                float ig = sigm(aI[r]), fg = sigm(aF[r]), gt = tanh_f(aG[r]), og = sigm(aO[r]);
                float cn = fg * cst[nt][r] + ig * gt;
                float hn = og * tanh_f(cn);
                int Lv = (int)(((r < 2) ? (Lp0 >> (16 * (r & 1))) : (Lp1 >> (16 * (r & 1)))) & 0xffffu);
                if (dir && t >= Lv) { cn = cst[nt][r]; hn = 0.0f; }   // backward: masked suffix stays 0
                cst[nt][r] = cn;
                u16 hbf = f2bf(hn);
                hw[(hrow + r) * 264 + cb + nt * 16] = hbf;            // h for next step (LDS)
                hsbase[(size_t)r * 256 + nt * 16] = hbf;              // history for k4 (in flight)
            }
            xc0 = xn0;
            xc1 = xn1;
        }

        // Barrier WITHOUT vmcnt drain: only LDS writes must be visible.
        asm volatile("s_waitcnt lgkmcnt(0)" ::: "memory");
        __builtin_amdgcn_sched_barrier(0);
        __builtin_amdgcn_s_barrier();
        __builtin_amdgcn_sched_barrier(0);
    }
}

// ---------------- K4: logits = log_softmax([hf;hb] @ out_W + out_b) ---------------
__global__ __launch_bounds__(256) void k4_proj(const u16* __restrict__ hs, const u16* __restrict__ outWb,
                                               const float* __restrict__ out_b, float* __restrict__ logits) {
    int r = blockIdx.x * 8 + (threadIdx.x >> 5);
    int n = threadIdx.x & 31;
    const u16* hf = hs + (size_t)r * 256;
    const u16* hbk = hs + 4194304ull + (size_t)r * 256;
    float acc = out_b[n];
#pragma unroll 4
    for (int k = 0; k < 256; k += 2) {
        u32 hv = *(const u32*)(const void*)(hf + k);
        acc += bf2f((u16)hv) * bf2f(outWb[k * 32 + n]);
        acc += bf2f((u16)(hv >> 16)) * bf2f(outWb[(k + 1) * 32 + n]);
    }
#pragma unroll 4
    for (int k = 0; k < 256; k += 2) {
        u32 hv = *(const u32*)(const void*)(hbk + k);
        acc += bf2f((u16)hv) * bf2f(outWb[(256 + k) * 32 + n]);
        acc += bf2f((u16)(hv >> 16)) * bf2f(outWb[(257 + k) * 32 + n]);
    }
    float m = acc;
#pragma unroll
    for (int d2 = 16; d2 >= 1; d2 >>= 1) m = fmaxf(m, __shfl_xor(m, d2, 32));
    float s = __expf(acc - m);
#pragma unroll
    for (int d2 = 16; d2 >= 1; d2 >>= 1) s += __shfl_xor(s, d2, 32);
    logits[(size_t)r * 32 + n] = acc - m - __logf(s);
}

// ---------------- K5: CRF forward + gold score -> out[b] --------------------------
__global__ __launch_bounds__(256) void k5_crf(const float* __restrict__ logits, const int* __restrict__ target,
                                              const int* __restrict__ seq_len, const float* __restrict__ trans,
                                              const float* __restrict__ start_trans, const float* __restrict__ end_trans,
                                              float* __restrict__ out) {
    int b = blockIdx.x;
    int tid = threadIdx.x;
    int L = seq_len[b];
    __shared__ float alpha[32];
    __shared__ float red[4];
    __shared__ float goldsh;

    // gold path score
    float part = 0.0f;
    for (int t = tid; t < 512; t += 256) {
        if (t < L) {
            int tg = target[b * 512 + t];
            part += logits[((size_t)(t * 32 + b)) * 32 + tg];
            if (t >= 1) part += trans[target[b * 512 + t - 1] * 32 + tg];
        }
    }
#pragma unroll
    for (int d2 = 32; d2 >= 1; d2 >>= 1) part += __shfl_xor(part, d2, 64);
    if ((tid & 63) == 0) red[tid >> 6] = part;
    __syncthreads();
    if (tid == 0) {
        float g = red[0] + red[1] + red[2] + red[3];
        g += start_trans[target[b * 512]];
        g += end_trans[target[b * 512 + L - 1]];
        goldsh = g;
    }
    if (tid < 32) alpha[tid] = logits[(size_t)b * 32 + tid] + start_trans[tid];
    __syncthreads();

    int j = tid >> 3, uu = tid & 7;
    float tr4[4];
#pragma unroll
    for (int r = 0; r < 4; ++r) tr4[r] = trans[(uu * 4 + r) * 32 + j];
    float e_next = logits[((size_t)(32 + b)) * 32 + j];
    for (int t = 1; t < 512; ++t) {
        float e = e_next;
        if (t < 511) e_next = logits[((size_t)((t + 1) * 32 + b)) * 32 + j];
        float a0 = alpha[uu * 4 + 0] + tr4[0];
        float a1 = alpha[uu * 4 + 1] + tr4[1];
        float a2 = alpha[uu * 4 + 2] + tr4[2];
        float a3 = alpha[uu * 4 + 3] + tr4[3];
        float m = fmaxf(fmaxf(a0, a1), fmaxf(a2, a3));
#pragma unroll
        for (int d2 = 4; d2 >= 1; d2 >>= 1) m = fmaxf(m, __shfl_xor(m, d2, 8));
        float ss = __expf(a0 - m) + __expf(a1 - m) + __expf(a2 - m) + __expf(a3 - m);
#pragma unroll
        for (int d2 = 4; d2 >= 1; d2 >>= 1) ss += __shfl_xor(ss, d2, 8);
        float nv = e + m + __logf(ss);
        __syncthreads();
        if (uu == 0 && t < L) alpha[j] = nv;
        __syncthreads();
    }
    if (tid < 32) {
        float v = alpha[tid] + end_trans[tid];
        float m = v;
#pragma unroll
        for (int d2 = 16; d2 >= 1; d2 >>= 1) m = fmaxf(m, __shfl_xor(m, d2, 32));
        float s2 = __expf(v - m);
#pragma unroll
        for (int d2 = 16; d2 >= 1; d2 >>= 1) s2 += __shfl_xor(s2, d2, 32);
        if (tid == 0) out[b] = m + __logf(s2) - goldsh;
    }
}

extern "C" void kernel_launch(void* const* d_in, const int* in_sizes, int n_in,
                              void* d_out, int out_size, void* d_ws, size_t ws_size,
                              hipStream_t stream) {
    if (ws_size < WS_NEED) return;  // workspace too small: fail cleanly, no OOB
    const int* chars = (const int*)d_in[0];
    const int* bigrams = (const int*)d_in[1];
    const int* seq_len = (const int*)d_in[2];
    const int* target = (const int*)d_in[3];
    const float* char_table = (const float*)d_in[4];
    const float* bigram_table = (const float*)d_in[5];
    const float* Wi_f = (const float*)d_in[6];
    const float* Wh_f = (const float*)d_in[7];
    const float* b_f = (const float*)d_in[8];
    const float* Wi_b = (const float*)d_in[9];
    const float* Wh_b = (const float*)d_in[10];
    const float* b_b = (const float*)d_in[11];
    const float* out_W = (const float*)d_in[12];
    const float* out_b = (const float*)d_in[13];
    const float* trans = (const float*)d_in[14];
    const float* start_trans = (const float*)d_in[15];
    const float* end_trans = (const float*)d_in[16];

    char* ws = (char*)d_ws;
    u16* emb = (u16*)(ws + O_EMB);
    u16* xg = (u16*)(ws + O_XG);
    u16* hs = (u16*)(ws + O_HS);
    float* logits = (float*)(ws + O_LOGITS);
    u16* WhT = (u16*)(ws + O_LOGITS);    // parked in logits region; dead before k4 writes logits
    u16* WiT = (u16*)(ws + O_WIT);
    u16* outWb = (u16*)(ws + O_OUTW);

    hipLaunchKernelGGL(k0_prep, dim3(4160), dim3(256), 0, stream, Wi_f, Wi_b, Wh_f, Wh_b, out_W, WiT, WhT, outWb);
    hipLaunchKernelGGL(k1_embed, dim3(8192), dim3(256), 0, stream, chars, bigrams, char_table, bigram_table, emb);
    hipLaunchKernelGGL(k2_gemm, dim3(256, 16, 2), dim3(256), 0, stream, emb, WiT, b_f, b_b, xg);
    hipLaunchKernelGGL(k3_lstm, dim3(4), dim3(256), 0, stream, xg, WhT, seq_len, hs);
    hipLaunchKernelGGL(k4_proj, dim3(2048), dim3(256), 0, stream, hs, outWb, out_b, logits);
    hipLaunchKernelGGL(k5_crf, dim3(32), dim3(256), 0, stream, logits, target, seq_len, trans, start_trans, end_trans,
                       (float*)d_out);
}